// Round 5
// baseline (173.125 us; speedup 1.0000x reference)
//
#include <hip/hip_runtime.h>

#define NB 2048
#define NJ 22
#define ND 128
#define ROW4 (NJ * ND / 4)  // 704 float4 per i-row

typedef float f32x4 __attribute__((ext_vector_type(4)));

// out[b][i][j][e] = Y[b][j][e] - Y[b][i][e] + bias[e],  Y = src @ W^T
__global__ __launch_bounds__(256, 4) void see_kernel(
    const float* __restrict__ src, const float* __restrict__ W,
    const float* __restrict__ bias, float* __restrict__ out) {
  __shared__ float YS[NJ * ND];  // [j][e], 11 KB — only LDS in the kernel

  const int b = blockIdx.x;
  const int t = threadIdx.x;
  const int e = t & 127;                                   // feature owned
  const int dh = __builtin_amdgcn_readfirstlane(t >> 7);   // wave-uniform 0/1

  // ---- W[e][dh*64 .. +63] into VGPRs (vector loads, W is L2-hot 64 KB) ----
  float w[64];
  {
    const f32x4* Wrow = reinterpret_cast<const f32x4*>(W + e * ND + dh * 64);
#pragma unroll
    for (int k = 0; k < 16; ++k) {
      f32x4 v = Wrow[k];
      w[4 * k + 0] = v.x;
      w[4 * k + 1] = v.y;
      w[4 * k + 2] = v.z;
      w[4 * k + 3] = v.w;
    }
  }

  // ---- GEMM: src read via SCALAR path (uniform address -> s_load + K$) ----
  // srcU is wave-uniform: b uniform, dh readfirstlane'd, j/k compile-time.
  const float* srcU = src + (size_t)b * NJ * ND + dh * 64;

  for (int c = 0; c < 2; ++c) {  // two chunks of 11 j-rows: VGPR/SGPR bounded
    float acc[11];
#pragma unroll
    for (int jj = 0; jj < 11; ++jj) {
      const float* sr = srcU + (c * 11 + jj) * ND;
      float a = 0.f;
#pragma unroll
      for (int k = 0; k < 64; ++k) a += sr[k] * w[k];  // v_fmac v, s, v
      acc[jj] = a;
    }
    if (dh == 0) {
#pragma unroll
      for (int jj = 0; jj < 11; ++jj) YS[(c * 11 + jj) * ND + e] = acc[jj];
    }
    __syncthreads();  // chunk's dh0 writes visible to dh1 waves
    if (dh == 1) {
#pragma unroll
      for (int jj = 0; jj < 11; ++jj) YS[(c * 11 + jj) * ND + e] += acc[jj];
    }
    // next chunk touches disjoint YS rows -> no barrier needed here
  }
  __syncthreads();  // YS complete

  // ---- streaming expansion: out[b][i][j][e] = YS[j][e] - YS[i][e] + b[e] ----
  // Flat float4 index in an i-row: q = jx*32 + e4, covered by q = t + 256*k.
  // This thread always writes rows {j0, j0+8, j0+16} at column e4.
  const int e4 = t & 31;
  const int j0 = t >> 5;  // 0..7
  const f32x4* YS4 = reinterpret_cast<const f32x4*>(YS);
  const f32x4 bb4 = reinterpret_cast<const f32x4*>(bias)[e4];

  f32x4 yj0 = YS4[j0 * 32 + e4] + bb4;
  f32x4 yj1 = YS4[(j0 + 8) * 32 + e4] + bb4;
  f32x4 yj2 = {0.f, 0.f, 0.f, 0.f};
  if (j0 < 6) yj2 = YS4[(j0 + 16) * 32 + e4] + bb4;

  f32x4* outB4 = reinterpret_cast<f32x4*>(out + (size_t)b * NJ * NJ * ND);

  for (int ii = 0; ii < NJ; ++ii) {
    f32x4 yi = YS4[ii * 32 + e4];  // 2 lanes/addr, 2-way = free
    f32x4* outRow4 = outB4 + (size_t)ii * ROW4;
    outRow4[t] = yj0 - yi;
    outRow4[t + 256] = yj1 - yi;
    if (j0 < 6) outRow4[t + 512] = yj2 - yi;
  }
}

extern "C" void kernel_launch(void* const* d_in, const int* in_sizes, int n_in,
                              void* d_out, int out_size, void* d_ws, size_t ws_size,
                              hipStream_t stream) {
  const float* src  = (const float*)d_in[0];  // [2048, 22, 128] f32
  const float* W    = (const float*)d_in[1];  // [128, 128] f32, W[e][d]
  const float* bias = (const float*)d_in[2];  // [128] f32
  float* out = (float*)d_out;                 // [2048, 22, 22, 128] f32

  see_kernel<<<NB, 256, 0, stream>>>(src, W, bias, out);
}

// Round 6
// 112.988 us; speedup vs baseline: 1.5322x; 1.5322x over previous
//
#include <hip/hip_runtime.h>

#define NB 2048
#define NJ 22
#define ND 128
#define NBAT 8
#define NBLK (NB / NBAT)     // 256 blocks = 1 per CU
#define JD (NJ * ND)         // 2816 floats per batch of src/Y
#define ROW4 (JD / 4)        // 704 float4 per i-row

typedef float f32x4 __attribute__((ext_vector_type(4)));

// Raw barrier: waits LDS ops only; global stores stay in flight across it.
__device__ __forceinline__ void bar_lgkm() {
  asm volatile("s_waitcnt lgkmcnt(0)" ::: "memory");
  __builtin_amdgcn_s_barrier();
  __builtin_amdgcn_sched_barrier(0);
}

// out[b][i][j][e] = Y[b][j][e] - Y[b][i][e] + bias[e],  Y = src @ W^T
// Persistent: 256 blocks x 8 batches, stores of batch k drain under GEMM k+1.
__global__ __launch_bounds__(256, 1) void see_kernel(
    const float* __restrict__ src, const float* __restrict__ W,
    const float* __restrict__ bias, float* __restrict__ out) {
  __shared__ float srcS[2][JD];  // double-buffered src tile (22.5 KB)
  __shared__ float YS[JD];       // Y tile (11 KB)

  const int t  = threadIdx.x;
  const int e  = t & 127;  // feature owned in GEMM
  const int dh = t >> 7;   // d-half (0/1)
  const int e4 = t & 31;   // float4 column in epilogue
  const int j0 = t >> 5;   // 0..7: epilogue rows {j0, j0+8, j0+16}

  // ---- W[e][dh*64 .. +63] into regs ONCE (reused for all 8 batches) ----
  float w[64];
  {
    const f32x4* Wrow = reinterpret_cast<const f32x4*>(W + e * ND + dh * 64);
#pragma unroll
    for (int k = 0; k < 16; ++k) {
      f32x4 v = Wrow[k];
      w[4 * k + 0] = v.x; w[4 * k + 1] = v.y;
      w[4 * k + 2] = v.z; w[4 * k + 3] = v.w;
    }
  }
  const f32x4 bb4 = reinterpret_cast<const f32x4*>(bias)[e4];

  const size_t b0 = (size_t)blockIdx.x * NBAT;

  // ---- prologue: stage src[b0] -> srcS[0] ----
  {
    const f32x4* g = reinterpret_cast<const f32x4*>(src + b0 * JD);
    f32x4* l = reinterpret_cast<f32x4*>(&srcS[0][0]);
    f32x4 r0 = g[t], r1 = g[t + 256], r2 = {0, 0, 0, 0};
    if (t < 192) r2 = g[t + 512];
    l[t] = r0; l[t + 256] = r1;
    if (t < 192) l[t + 512] = r2;
  }
  bar_lgkm();  // srcS[0] visible to all waves

  for (int bi = 0; bi < NBAT; ++bi) {
    const float* sC = &srcS[bi & 1][0];

    // ---- GEMM: acc[j] = src[b][j][dh*64..+63] . w   (LDS broadcast reads) ----
    float acc[NJ];
#pragma unroll
    for (int j = 0; j < NJ; ++j) {
      const f32x4* s4 = reinterpret_cast<const f32x4*>(sC + j * ND + dh * 64);
      float a = 0.f;
#pragma unroll
      for (int k = 0; k < 16; ++k) {
        f32x4 s = s4[k];  // wave-uniform address -> broadcast
        a += s.x * w[4 * k + 0];
        a += s.y * w[4 * k + 1];
        a += s.z * w[4 * k + 2];
        a += s.w * w[4 * k + 3];
      }
      acc[j] = a;
    }
    if (dh == 0) {
#pragma unroll
      for (int j = 0; j < NJ; ++j) YS[j * ND + e] = acc[j];
    }
    bar_lgkm();  // dh0 partials visible
    if (dh == 1) {
#pragma unroll
      for (int j = 0; j < NJ; ++j) YS[j * ND + e] += acc[j];
    }
    bar_lgkm();  // YS final visible

    // ---- prefetch next src tile into regs BEFORE stores ----
    // (loads older than the stores -> compiler emits a COUNTED vmcnt before
    //  the ds_writes below, never vmcnt(0): stores keep draining.)
    f32x4 p0 = {0,0,0,0}, p1 = {0,0,0,0}, p2 = {0,0,0,0};
    const bool havePf = (bi + 1 < NBAT);
    if (havePf) {
      const f32x4* g = reinterpret_cast<const f32x4*>(src + (b0 + bi + 1) * JD);
      p0 = g[t]; p1 = g[t + 256];
      if (t < 192) p2 = g[t + 512];
    }
    __builtin_amdgcn_sched_barrier(0);  // pin prefetch loads before stores

    // ---- epilogue: out[b][i][j][e] = YS[j][e] - YS[i][e] + bias[e] ----
    const f32x4* YS4 = reinterpret_cast<const f32x4*>(YS);
    f32x4 yj0 = YS4[j0 * 32 + e4] + bb4;
    f32x4 yj1 = YS4[(j0 + 8) * 32 + e4] + bb4;
    f32x4 yj2 = {0, 0, 0, 0};
    if (j0 < 6) yj2 = YS4[(j0 + 16) * 32 + e4] + bb4;

    f32x4* outB4 =
        reinterpret_cast<f32x4*>(out + (b0 + bi) * (size_t)NJ * JD);
    for (int ii = 0; ii < NJ; ++ii) {
      f32x4 yi = YS4[ii * 32 + e4];
      f32x4* outRow4 = outB4 + (size_t)ii * ROW4;
      __builtin_nontemporal_store(yj0 - yi, outRow4 + t);
      __builtin_nontemporal_store(yj1 - yi, outRow4 + t + 256);
      if (j0 < 6) __builtin_nontemporal_store(yj2 - yi, outRow4 + t + 512);
    }
    __builtin_amdgcn_sched_barrier(0);  // pin stores before srcS ds_writes

    // ---- write prefetched tile to the other srcS buffer ----
    if (havePf) {
      f32x4* l = reinterpret_cast<f32x4*>(&srcS[(bi + 1) & 1][0]);
      l[t] = p0; l[t + 256] = p1;
      if (t < 192) l[t + 512] = p2;
      bar_lgkm();  // srcS[next] visible; also gates YS overwrite next iter
    }
  }
}

extern "C" void kernel_launch(void* const* d_in, const int* in_sizes, int n_in,
                              void* d_out, int out_size, void* d_ws, size_t ws_size,
                              hipStream_t stream) {
  const float* src  = (const float*)d_in[0];  // [2048, 22, 128] f32
  const float* W    = (const float*)d_in[1];  // [128, 128] f32, W[e][d]
  const float* bias = (const float*)d_in[2];  // [128] f32
  float* out = (float*)d_out;                 // [2048, 22, 22, 128] f32

  see_kernel<<<NBLK, 256, 0, stream>>>(src, W, bias, out);
}